// Round 6
// baseline (331.243 us; speedup 1.0000x reference)
//
#include <hip/hip_runtime.h>
#include <stdint.h>

// ReconBlock: 3-axis 3-tap submanifold conv (gathered neighbors) + BN(inference)
// + sigmoid per branch, branches summed, gated by input features.
// fp32 in/out; compute via bf16 MFMA (16x16x32).
//
// R6: force memory-level parallelism. R3/R5 evidence: time pinned at ~150us
// with everything idle; VGPR_Count=44 proves the max-occupancy scheduler sank
// every gather to its use (1 load in flight per wave, ~600-900cyc each, ~30
// serialized rounds/tile = the observed 1500 cyc/tile/CU @16 waves).
// Fix: issue ALL 28 dwordx4 gathers for the wave's 2 tiles into live regs,
// then sched_barrier(0) so nothing can be reordered across the batch; compute
// both tiles after. launch_bounds(256,2) raises the VGPR cap to 256.

typedef __attribute__((ext_vector_type(8))) __bf16 bf16x8;
typedef __attribute__((ext_vector_type(8))) unsigned short u16x8;
typedef __attribute__((ext_vector_type(4))) float f32x4;
typedef __attribute__((ext_vector_type(2))) float f32x2;
typedef __attribute__((ext_vector_type(4))) unsigned u32x4;

constexpr int NVOX    = 1000000;
constexpr int NTILES  = NVOX / 16;                  // 62500
constexpr int TPW     = 2;                          // tiles per wave (exact: 31250 waves)
constexpr int WPB     = 4;                          // waves per block
constexpr int NWAVES  = (NTILES + TPW - 1) / TPW;   // 31250
constexpr int NBLOCKS = (NWAVES + WPB - 1) / WPB;   // 7813
constexpr float LOG2E = 1.4426950408889634f;

// ws layout: bf16 W frags [18][64][8] (18432 B), then A[3][32], B[3][32] fp32
constexpr int WS_WELEMS = 18 * 64 * 8;              // 9216 bf16 elems

__global__ __launch_bounds__(256) void prep_kernel(
    const float* __restrict__ Wt,    // [3][3][32][32]
    const float* __restrict__ gma, const float* __restrict__ bta,
    const float* __restrict__ mea, const float* __restrict__ var,
    unsigned short* __restrict__ wsW, float* __restrict__ wsA,
    float* __restrict__ wsB)
{
    int tid = blockIdx.x * 256 + threadIdx.x;
    if (tid < WS_WELEMS) {
        int f    = tid >> 9;          // fragment id = (br*3+t)*2+h
        int rem  = tid & 511;
        int lane = rem >> 3;
        int j    = rem & 7;
        int br = f / 6, t = (f >> 1) % 3, h = f & 1;
        int n = lane & 15, quad = lane >> 4;
        // B[k=quad*8+j][col]; col interleave: half h = original channel 2n+h
        float w = Wt[((br * 3 + t) * 32 + quad * 8 + j) * 32 + 2 * n + h];
        union { float f; unsigned u; } c; c.f = w;
        wsW[(f * 64 + lane) * 8 + j] = (unsigned short)((c.u + 0x8000u) >> 16);
    } else if (tid < WS_WELEMS + 96) {
        int i = tid - WS_WELEMS;      // br*32 + c
        float s = gma[i] * __frsqrt_rn(var[i] + 1e-5f);
        wsA[i] = -s * LOG2E;
        wsB[i] = (mea[i] * s - bta[i]) * LOG2E;
    }
}

__device__ __forceinline__ unsigned pack_bf(float a, float b) {
    union { float f; unsigned u; } ca, cb; ca.f = a; cb.f = b;
    // d = hi16(a+0x8000) | hi16(b+0x8000)<<16  (one v_perm)
    return __builtin_amdgcn_perm(cb.u + 0x8000u, ca.u + 0x8000u, 0x07060302u);
}
// convert 8 fp32 -> bf16x8, zeroed when !act (branchless)
__device__ __forceinline__ bf16x8 cvt_mask(f32x4 lo, f32x4 hi, bool act) {
    unsigned m = act ? 0xffffffffu : 0u;
    union { unsigned u[4]; bf16x8 v; } r;
    r.u[0] = pack_bf(lo[0], lo[1]) & m; r.u[1] = pack_bf(lo[2], lo[3]) & m;
    r.u[2] = pack_bf(hi[0], hi[1]) & m; r.u[3] = pack_bf(hi[2], hi[3]) & m;
    return r.v;
}

__global__ __launch_bounds__(256, 2) void recon_kernel(
    const float*          __restrict__ feat,   // [N][32]
    const int*            __restrict__ nprev,  // [3][N]
    const int*            __restrict__ nnext,  // [3][N]
    const unsigned short* __restrict__ wsW,    // [18][64][8] bf16
    const float*          __restrict__ wsA,    // [3][32]
    const float*          __restrict__ wsB,    // [3][32]
    float*                __restrict__ out)    // [N][32]
{
    __shared__ unsigned short sW[WS_WELEMS];   // 18432 B

    // ---- cooperative W copy ws -> LDS (1152 x 16 B chunks)
    {
        const u32x4* src = (const u32x4*)wsW;
        u32x4*       dst = (u32x4*)sW;
        #pragma unroll
        for (int k = 0; k < 5; ++k) {
            int i = threadIdx.x + k * 256;
            if (i < WS_WELEMS / 8) dst[i] = src[i];
        }
    }
    __syncthreads();

    const int lane = threadIdx.x & 63;
    const int n    = lane & 15;   // lane owns out channels 2n, 2n+1
    const int quad = lane >> 4;

    // XCD-aware swizzle: contiguous 1/8th of voxel range per XCD
    int b   = blockIdx.x;
    int per = NBLOCKS / 8;
    int bs  = (b < per * 8) ? ((b & 7) * per + (b >> 3)) : b;
    int wv  = bs * WPB + (threadIdx.x >> 6);

    const int t0 = wv * TPW;
    if (t0 >= NTILES) return;     // valid waves always have 2 full tiles

    // ---- folded BN consts for this lane's channels (2n, 2n+1)
    f32x2 A_[3], B_[3];
    #pragma unroll
    for (int br = 0; br < 3; ++br) {
        A_[br] = *(const f32x2*)(wsA + br * 32 + 2 * n);
        B_[br] = *(const f32x2*)(wsB + br * 32 + 2 * n);
    }

    // ---- all 12 neighbor indices for both tiles (independent, batched)
    int ip[TPW][3], inx[TPW][3];
    #pragma unroll
    for (int tt = 0; tt < TPW; ++tt) {
        int row = (t0 + tt) * 16 + n;
        #pragma unroll
        for (int a = 0; a < 3; ++a) {
            ip[tt][a]  = nprev[a * NVOX + row];
            inx[tt][a] = nnext[a * NVOX + row];
        }
    }

    // ---- LOAD PHASE: all 28 dwordx4 gathers live at once (112 VGPRs)
    //      tap order: 0=self, 1..3=prev[a], 4..6=next[a]
    f32x4 P[TPW][7][2];
    #pragma unroll
    for (int tt = 0; tt < TPW; ++tt) {
        int base = (t0 + tt) * 16;
        int row  = base + n;
        int r[7];
        r[0] = row;
        #pragma unroll
        for (int a = 0; a < 3; ++a) {
            r[1 + a] = ip[tt][a]  >= 0 ? ip[tt][a]  : row;   // v_cndmask
            r[4 + a] = inx[tt][a] >= 0 ? inx[tt][a] : row;
        }
        #pragma unroll
        for (int t = 0; t < 7; ++t) {
            const f32x4* p = (const f32x4*)(feat + r[t] * 32 + quad * 8);
            P[tt][t][0] = p[0];
            P[tt][t][1] = p[1];
        }
    }
    // Nothing may be scheduled across this point: the 28 loads stay batched
    // above, all outstanding; compute below consumes them.
    __builtin_amdgcn_sched_barrier(0);

    // ---- COMPUTE PHASE
    #pragma unroll
    for (int tt = 0; tt < TPW; ++tt) {
        int base = (t0 + tt) * 16;

        bf16x8 Af[7];
        Af[0] = cvt_mask(P[tt][0][0], P[tt][0][1], true);
        #pragma unroll
        for (int a = 0; a < 3; ++a) {
            Af[1 + a] = cvt_mask(P[tt][1 + a][0], P[tt][1 + a][1], ip[tt][a]  >= 0);
            Af[4 + a] = cvt_mask(P[tt][4 + a][0], P[tt][4 + a][1], inx[tt][a] >= 0);
        }

        const u16x8* sWf = (const u16x8*)sW;   // frag f, lane l at [f*64 + l]
        f32x4 acc0 = {0.f, 0.f, 0.f, 0.f}, acc1 = {0.f, 0.f, 0.f, 0.f};
        #pragma unroll
        for (int br = 0; br < 3; ++br) {
            f32x4 c0 = {0.f, 0.f, 0.f, 0.f}, c1 = {0.f, 0.f, 0.f, 0.f};
            bf16x8 w0 = __builtin_bit_cast(bf16x8, sWf[(br*6 + 0) * 64 + lane]);
            bf16x8 w1 = __builtin_bit_cast(bf16x8, sWf[(br*6 + 1) * 64 + lane]);
            c0 = __builtin_amdgcn_mfma_f32_16x16x32_bf16(Af[1 + br], w0, c0, 0, 0, 0);
            c1 = __builtin_amdgcn_mfma_f32_16x16x32_bf16(Af[1 + br], w1, c1, 0, 0, 0);
            bf16x8 w2 = __builtin_bit_cast(bf16x8, sWf[(br*6 + 2) * 64 + lane]);
            bf16x8 w3 = __builtin_bit_cast(bf16x8, sWf[(br*6 + 3) * 64 + lane]);
            c0 = __builtin_amdgcn_mfma_f32_16x16x32_bf16(Af[0],      w2, c0, 0, 0, 0);
            c1 = __builtin_amdgcn_mfma_f32_16x16x32_bf16(Af[0],      w3, c1, 0, 0, 0);
            bf16x8 w4 = __builtin_bit_cast(bf16x8, sWf[(br*6 + 4) * 64 + lane]);
            bf16x8 w5 = __builtin_bit_cast(bf16x8, sWf[(br*6 + 5) * 64 + lane]);
            c0 = __builtin_amdgcn_mfma_f32_16x16x32_bf16(Af[4 + br], w4, c0, 0, 0, 0);
            c1 = __builtin_amdgcn_mfma_f32_16x16x32_bf16(Af[4 + br], w5, c1, 0, 0, 0);
            float a0 = A_[br][0], b0 = B_[br][0], a1 = A_[br][1], b1 = B_[br][1];
            #pragma unroll
            for (int r = 0; r < 4; ++r) {
                float e0 = __builtin_amdgcn_exp2f(__builtin_fmaf(c0[r], a0, b0));
                float e1 = __builtin_amdgcn_exp2f(__builtin_fmaf(c1[r], a1, b1));
                acc0[r] += __builtin_amdgcn_rcpf(1.0f + e0);
                acc1[r] += __builtin_amdgcn_rcpf(1.0f + e1);
            }
        }

        // ---- gate by input features and store (feat rows L1-hot from self tap)
        #pragma unroll
        for (int r = 0; r < 4; ++r) {
            int vrow = base + quad * 4 + r;
            f32x2 fv = *(const f32x2*)(feat + vrow * 32 + 2 * n);
            f32x2 ov = { acc0[r] * fv[0], acc1[r] * fv[1] };
            *(f32x2*)(out + vrow * 32 + 2 * n) = ov;
        }
    }
}

extern "C" void kernel_launch(void* const* d_in, const int* in_sizes, int n_in,
                              void* d_out, int out_size, void* d_ws, size_t ws_size,
                              hipStream_t stream) {
    const float* feat  = (const float*)d_in[0];
    const int*   nprev = (const int*)d_in[1];
    const int*   nnext = (const int*)d_in[2];
    const float* Wt    = (const float*)d_in[3];
    const float* gma   = (const float*)d_in[4];
    const float* bta   = (const float*)d_in[5];
    const float* mea   = (const float*)d_in[6];
    const float* var   = (const float*)d_in[7];
    float*       o     = (float*)d_out;

    unsigned short* wsW = (unsigned short*)d_ws;
    float*          wsA = (float*)((char*)d_ws + WS_WELEMS * 2);
    float*          wsB = wsA + 96;

    prep_kernel<<<(WS_WELEMS + 96 + 255) / 256, 256, 0, stream>>>(
        Wt, gma, bta, mea, var, wsW, wsA, wsB);
    recon_kernel<<<NBLOCKS, 256, 0, stream>>>(feat, nprev, nnext,
                                              wsW, wsA, wsB, o);
}